// Round 6
// baseline (608.575 us; speedup 1.0000x reference)
//
#include <hip/hip_runtime.h>
#include <stdint.h>

#define DM 1024
#define DF 4096
#define NE 8
#define NTOK 8192   // B*S = 4*2048
#define MT128 72    // >= max 128-row tiles (71), divisible by 8

typedef __attribute__((ext_vector_type(8))) short short8;
typedef __attribute__((ext_vector_type(8))) unsigned short ushort8v;
typedef __attribute__((ext_vector_type(4))) float floatx4;

__device__ inline unsigned short f2bf(float f) {
    union { float f; unsigned u; } v; v.f = f;
    unsigned u = v.u;
    u += 0x7fffu + ((u >> 16) & 1u);   // round-to-nearest-even
    return (unsigned short)(u >> 16);
}

#define GLDS(g, l) __builtin_amdgcn_global_load_lds( \
    (const __attribute__((address_space(1))) void*)(g), \
    (__attribute__((address_space(3))) void*)(l), 16, 0, 0)

#define VMW(N)  asm volatile("s_waitcnt vmcnt(" #N ")" ::: "memory")
#define SCHED0  __builtin_amdgcn_sched_barrier(0)
#define BAR     __builtin_amdgcn_s_barrier()

// ======= fused gate + weight-transpose: one grid, branch on blockIdx =======
// blocks [0, NTOK/4): gating, 4 waves/block, one token per wave, fp64 acc; also emits bf16 x.
// blocks [NTOK/4, ...): tiled transpose+convert w1 then w2: [E][R][C] f32 -> [E][C][R] bf16.
__global__ __launch_bounds__(256) void gate_transpose(
    const float* __restrict__ x, const float* __restrict__ gw, const float* __restrict__ gb,
    int* __restrict__ top1, unsigned short* __restrict__ xb,
    const float* __restrict__ w1, unsigned short* __restrict__ w1t,
    const float* __restrict__ w2, unsigned short* __restrict__ w2t) {
    constexpr int GATE_BLKS = NTOK / 4;               // 2048
    constexpr int NT1 = NE * (DM / 64) * (DF / 64);   // 8192 tiles per weight
    __shared__ float tile[64][65];
    int bid = blockIdx.x;
    int tid = threadIdx.x;

    if (bid < GATE_BLKS) {
        int wave = tid >> 6, lane = tid & 63;
        int t = bid * 4 + wave;
        const float* xr = x + (size_t)t * DM;
        unsigned short* xbr = xb + (size_t)t * DM;
        double acc[NE];
#pragma unroll
        for (int e = 0; e < NE; ++e) acc[e] = 0.0;
        for (int j = 0; j < DM / 64; ++j) {
            int d = j * 64 + lane;
            float xf = xr[d];
            xbr[d] = f2bf(xf);
            double xv = (double)xf;
            const float* g = gw + (size_t)d * NE;
#pragma unroll
            for (int e = 0; e < NE; ++e) acc[e] = fma(xv, (double)g[e], acc[e]);
        }
#pragma unroll
        for (int e = 0; e < NE; ++e) {
            for (int off = 32; off > 0; off >>= 1)
                acc[e] += __shfl_down(acc[e], off, 64);
        }
        if (lane == 0) {
            int best = 0;
            double bv = acc[0] + (double)gb[0];
            for (int e = 1; e < NE; ++e) {
                double v = acc[e] + (double)gb[e];
                if (v > bv) { bv = v; best = e; }   // strict > == first-max (jnp.argmax)
            }
            top1[t] = best;
        }
        return;
    }

    bid -= GATE_BLKS;
    const float* src; unsigned short* dst; int R, C;
    if (bid < NT1) { src = w1; dst = w1t; R = DM; C = DF; }
    else           { bid -= NT1; src = w2; dst = w2t; R = DF; C = DM; }
    int tilesR = R >> 6, tilesC = C >> 6;
    int e = bid / (tilesR * tilesC);
    int rem = bid % (tilesR * tilesC);
    int tr = rem / tilesC, tc = rem % tilesC;
    const float* s = src + (size_t)e * R * C + (size_t)(tr * 64) * C + tc * 64;
    unsigned short* d = dst + (size_t)e * R * C + (size_t)(tc * 64) * R + tr * 64;
#pragma unroll
    for (int i = 0; i < 4; ++i) {
        int idx = i * 256 + tid;          // 0..1023
        int r = idx >> 4, c4 = (idx & 15) * 4;
        float4 v = *(const float4*)(s + (size_t)r * C + c4);
        tile[r][c4 + 0] = v.x; tile[r][c4 + 1] = v.y;
        tile[r][c4 + 2] = v.z; tile[r][c4 + 3] = v.w;
    }
    __syncthreads();
#pragma unroll
    for (int i = 0; i < 2; ++i) {
        int idx = i * 256 + tid;          // 0..511
        int c = idx >> 3, r8 = (idx & 7) * 8;
        ushort8v o;
#pragma unroll
        for (int j = 0; j < 8; ++j) o[j] = f2bf(tile[r8 + j][c]);
        *(ushort8v*)(d + (size_t)c * R + r8) = o;
    }
}

// ======= fused count+prefix+scatter+table-build: ONE single-block kernel, LDS state =======
// ctrl ints used downstream: [25] ntiles128, [32+3i..] tile table (expert, rowbase, rows).
__global__ __launch_bounds__(1024) void sort_kernel(const int* __restrict__ top1,
                                                    int* __restrict__ ctrl,
                                                    int* __restrict__ perm) {
    __shared__ int cnt[NE];
    __shared__ int cur[NE];
    int tid = threadIdx.x, lane = tid & 63;
    if (tid < NE) cnt[tid] = 0;
    __syncthreads();
    int ev[8];
#pragma unroll
    for (int j = 0; j < 8; ++j) ev[j] = top1[j * 1024 + tid];
    // wave-ballot counting, one LDS atomic per (wave, expert)
#pragma unroll
    for (int e = 0; e < NE; ++e) {
        int c = 0;
#pragma unroll
        for (int j = 0; j < 8; ++j) {
            unsigned long long m = __ballot(ev[j] == e);
            c += __popcll(m);
        }
        if (lane == 0) atomicAdd(&cnt[e], c);
    }
    __syncthreads();
    if (tid == 0) {
        int s = 0, t128 = 0;
        for (int e = 0; e < NE; ++e) {
            int c = cnt[e];
            cur[e] = s;
            for (int m = 0; m * 128 < c; ++m) {
                ctrl[32 + 3 * t128] = e;
                ctrl[33 + 3 * t128] = s + m * 128;
                int rr = c - m * 128;
                ctrl[34 + 3 * t128] = rr < 128 ? rr : 128;
                ++t128;
            }
            s += c;
        }
        ctrl[25] = t128;
    }
    __syncthreads();
    // scatter: wave-aggregated LDS cursor bumps (order within expert is arbitrary — OK)
#pragma unroll
    for (int j = 0; j < 8; ++j) {
        int e = ev[j];
#pragma unroll
        for (int ex = 0; ex < NE; ++ex) {
            unsigned long long m = __ballot(e == ex);
            if (m == 0ull) continue;
            int leader = __ffsll((long long)m) - 1;
            int base = 0;
            if (lane == leader) base = atomicAdd(&cur[ex], __popcll(m));
            base = __shfl(base, leader, 64);
            if (e == ex) {
                int pos = __popcll(m & ((1ull << lane) - 1ull));
                perm[base + pos] = j * 1024 + tid;   // compacted position -> token id
            }
        }
    }
}

// ================= FFN GEMM: 128x128 tile, 4 waves, ring-4 BK=32 slabs, counted vmcnt ===========
// ROUND 6: geometry change only — schedule & vmcnt ledger bit-identical to the verified
// 256x256 kernel. 64 KiB LDS -> 2 blocks/CU (was 128 KiB -> 1/CU): co-resident blocks fill
// each other's barrier/prologue stalls (m114), and 4x block count shrinks the dispatch-round
// quantization tail (FFN2 was stuck at 62% CU coverage).
// LDS slab: [128 rows][4 slots][8 bf16] = 8 KiB; slot s' holds global k-chunk s'^((row>>1)&3)
// (pre-swizzled GLOBAL source, linear GLDS dest). Fragment ds_read_b128 -> 2-way banks (free).
// Schedule (T3+T4+T5): stage 3 slabs ahead; ONE s_barrier per slab (16 MFMA/wave/barrier);
// per-wave vmcnt(8) before the slab-end barrier => slab s+1 fully landed after it.
// Ring overwrite safety: slab s+3 -> buf[(s-1)&3], drained before slab s-1's end barrier.
// All ring indices compile-time (x4 unroll + peeled tail); vmcnt ledger counts ONLY the 4
// GLDS/slab (VMW's "memory" clobber pins GLDS ordering; ds_reads are C-level loads).
// Tail peel: vmcnt 8 / 4 / 0 literals.
#define F_SLAB(u, SU, STG, W) do { \
    if (STG) { \
        int kk_ = ((SU) + 3) * 32; \
        GLDS(ap0 + kk_, &As[((u) + 3) & 3][(size_t)tid * 8]); \
        GLDS(ap1 + kk_, &As[((u) + 3) & 3][(size_t)(256 + tid) * 8]); \
        GLDS(bp0 + kk_, &Bs[((u) + 3) & 3][(size_t)tid * 8]); \
        GLDS(bp1 + kk_, &Bs[((u) + 3) & 3][(size_t)(256 + tid) * 8]); \
    } \
    short8 bf[4], af[4]; \
    _Pragma("unroll") \
    for (int n_ = 0; n_ < 4; ++n_) bf[n_] = *(const short8*)&Bs[u][boff[n_]]; \
    _Pragma("unroll") \
    for (int m_ = 0; m_ < 4; ++m_) af[m_] = *(const short8*)&As[u][aoff[m_]]; \
    __builtin_amdgcn_s_setprio(1); \
    _Pragma("unroll") \
    for (int m_ = 0; m_ < 4; ++m_) \
        _Pragma("unroll") \
        for (int n_ = 0; n_ < 4; ++n_) \
            acc[m_][n_] = __builtin_amdgcn_mfma_f32_16x16x32_bf16(af[m_], bf[n_], acc[m_][n_], 0, 0, 0); \
    __builtin_amdgcn_s_setprio(0); \
    W; SCHED0; BAR; \
} while (0)

template<bool FFN1>
__global__ __launch_bounds__(256, 2) void ffn_gemm(
    const unsigned short* __restrict__ A,    // FFN1: xb [NTOK][DM]; FFN2: H [NTOK][DF] compacted
    const unsigned short* __restrict__ Bt,   // FFN1: w1t [E][DF][DM]; FFN2: w2t [E][DM][DF]
    const float* __restrict__ bias,          // b1 [E][DF] / b2 [E][DM]
    const int* __restrict__ ctrl,
    const int* __restrict__ perm,
    unsigned short* __restrict__ Hout,       // FFN1 out
    float* __restrict__ Yout) {              // FFN2 out
    constexpr int K = FFN1 ? DM : DF;        // 1024 / 4096
    constexpr int N = FFN1 ? DF : DM;        // 4096 / 1024
    constexpr int NT = N / 128;              // 32 / 8
    constexpr int NKI = K / 32;              // 32 / 128 slabs (both divisible by 4)
    constexpr int SLABSZ = 128 * 32;         // 4096 ushorts = 8 KiB
    constexpr int G = 8;

    // XCD-bijective remap + nt-major group order
    int nwg = gridDim.x;
    int bo = blockIdx.x;
    int q = nwg >> 3, r = nwg & 7;
    int xcd = bo & 7, lid = bo >> 3;
    int b = (xcd < r ? xcd * (q + 1) : r * (q + 1) + (xcd - r) * q) + lid;

    int grp = b / (G * NT);
    int ii = b % (G * NT);
    int nt = ii / G;
    int til = grp * G + (ii % G);
    if (til >= ctrl[25]) return;
    int e       = ctrl[32 + 3 * til];
    int rowbase = ctrl[33 + 3 * til];
    int rows    = ctrl[34 + 3 * til];

    __shared__ __align__(16) unsigned short As[4][SLABSZ];
    __shared__ __align__(16) unsigned short Bs[4][SLABSZ];

    int tid = threadIdx.x, lane = tid & 63, wave = tid >> 6;
    int wm = (wave & 1) * 64;     // 0 / 64
    int wn = (wave >> 1) * 64;    // 0 / 64

    // staging: each thread stages 2 chunks/slab per operand: rows tid>>2 and 64+(tid>>2)
    int rA0 = tid >> 2, rA1 = 64 + (tid >> 2);
    int kofs = ((tid & 3) ^ ((tid >> 3) & 3)) * 8;   // pre-swizzled global k-chunk
    // ((64+r)>>1)&3 == ((r>>1)+32)&3 == (r>>1)&3 -> same kofs valid for both rows
    int c0 = rowbase + (rA0 < rows ? rA0 : rows - 1);
    int c1 = rowbase + (rA1 < rows ? rA1 : rows - 1);
    const unsigned short* ap0;
    const unsigned short* ap1;
    if (FFN1) {
        ap0 = A + (size_t)perm[c0] * K + kofs;
        ap1 = A + (size_t)perm[c1] * K + kofs;
    } else {
        ap0 = A + (size_t)c0 * K + kofs;
        ap1 = A + (size_t)c1 * K + kofs;
    }
    const unsigned short* bb  = Bt + (size_t)e * N * K + (size_t)(nt * 128) * K + kofs;
    const unsigned short* bp0 = bb + (size_t)rA0 * K;
    const unsigned short* bp1 = bb + (size_t)rA1 * K;

    // fragment LDS offsets (ushort units), constant per lane; chunk g=lane>>4 at slot g^((R>>1)&3)
    int aoff[4], boff[4];
#pragma unroll
    for (int m = 0; m < 4; ++m) {
        int R = wm + m * 16 + (lane & 15);
        aoff[m] = R * 32 + (((lane >> 4) ^ ((R >> 1) & 3)) * 8);
    }
#pragma unroll
    for (int n = 0; n < 4; ++n) {
        int R = wn + n * 16 + (lane & 15);
        boff[n] = R * 32 + (((lane >> 4) ^ ((R >> 1) & 3)) * 8);
    }

    floatx4 acc[4][4];
#pragma unroll
    for (int i = 0; i < 4; ++i)
#pragma unroll
        for (int j = 0; j < 4; ++j) acc[i][j] = floatx4{0.f, 0.f, 0.f, 0.f};

    // prologue: stage slabs 0,1,2 (12 GLDS in flight); vmcnt(8) -> slab 0 landed
#pragma unroll
    for (int s = 0; s < 3; ++s) {
        GLDS(ap0 + s * 32, &As[s][(size_t)tid * 8]);
        GLDS(ap1 + s * 32, &As[s][(size_t)(256 + tid) * 8]);
        GLDS(bp0 + s * 32, &Bs[s][(size_t)tid * 8]);
        GLDS(bp1 + s * 32, &Bs[s][(size_t)(256 + tid) * 8]);
    }
    VMW(8); SCHED0; BAR;

#pragma unroll 1
    for (int s = 0; s < NKI - 4; s += 4) {   // each iter: slabs s..s+3, staging s+3..s+6
        F_SLAB(0, s + 0, 1, VMW(8));
        F_SLAB(1, s + 1, 1, VMW(8));
        F_SLAB(2, s + 2, 1, VMW(8));
        F_SLAB(3, s + 3, 1, VMW(8));
    }
    // tail: slabs NKI-4..NKI-1 (first stages slab NKI-1; then drain 8 -> 4 -> 0)
    F_SLAB(0, NKI - 4, 1, VMW(8));
    F_SLAB(1, NKI - 3, 0, VMW(4));
    F_SLAB(2, NKI - 2, 0, VMW(0));
    F_SLAB(3, NKI - 1, 0, (void)0);

    // epilogue; C/D layout: col = lane&15, row = (lane>>4)*4 + reg
    int col0 = nt * 128 + wn + (lane & 15);
    int rowq = (lane >> 4) * 4;
    float bv[4];
#pragma unroll
    for (int n = 0; n < 4; ++n) bv[n] = bias[e * N + col0 + n * 16];

#pragma unroll
    for (int m = 0; m < 4; ++m) {
#pragma unroll
        for (int r2 = 0; r2 < 4; ++r2) {
            int lr = wm + m * 16 + rowq + r2;
            if (lr < rows) {
                if (FFN1) {
                    unsigned short* hr = Hout + (size_t)(rowbase + lr) * DF + col0;
#pragma unroll
                    for (int n = 0; n < 4; ++n) {
                        float v = acc[m][n][r2] + bv[n];
                        v = v > 0.f ? v : 0.f;
                        hr[n * 16] = f2bf(v);
                    }
                } else {
                    float* yr = Yout + (size_t)perm[rowbase + lr] * DM + col0;
#pragma unroll
                    for (int n = 0; n < 4; ++n)
                        yr[n * 16] = acc[m][n][r2] + bv[n];
                }
            }
        }
    }
}
#undef F_SLAB

extern "C" void kernel_launch(void* const* d_in, const int* in_sizes, int n_in,
                              void* d_out, int out_size, void* d_ws, size_t ws_size,
                              hipStream_t stream) {
    const float* x  = (const float*)d_in[0];
    const float* w1 = (const float*)d_in[1];
    const float* b1 = (const float*)d_in[2];
    const float* w2 = (const float*)d_in[3];
    const float* b2 = (const float*)d_in[4];
    const float* gw = (const float*)d_in[5];
    const float* gb = (const float*)d_in[6];
    float* out = (float*)d_out;

    // workspace carve-up
    char* ws = (char*)d_ws;
    int* ctrl = (int*)ws;                                   // 2 KiB control block
    int* top1 = (int*)(ws + 2048);                          // 8192 ints
    int* perm = (int*)(ws + 2048 + 32768);                  // 8192 ints
    size_t o = 67584;                                       // 256B-aligned
    unsigned short* xb  = (unsigned short*)(ws + o);        o += (size_t)NTOK * DM * 2;      // 16.8 MB
    unsigned short* w1t = (unsigned short*)(ws + o);        o += (size_t)NE * DM * DF * 2;   // 67 MB
    unsigned short* w2t = (unsigned short*)(ws + o);        o += (size_t)NE * DM * DF * 2;   // 67 MB
    unsigned short* H   = (unsigned short*)(ws + o);        // 67 MB  (total ~218 MB)

    // 4 dispatches: fused gate+transpose, fused sort, ffn1, ffn2
    gate_transpose<<<NTOK / 4 + 2 * NE * (DM / 64) * (DF / 64), 256, 0, stream>>>(
        x, gw, gb, top1, xb, w1, w1t, w2, w2t);
    sort_kernel<<<1, 1024, 0, stream>>>(top1, ctrl, perm);
    ffn_gemm<true ><<<MT128 * (DF / 128), 256, 0, stream>>>(xb, w1t, b1, ctrl, perm, H, nullptr);
    ffn_gemm<false><<<MT128 * (DM / 128), 256, 0, stream>>>(H, w2t, b2, ctrl, perm, nullptr, out);
}

// Round 7
// 590.435 us; speedup vs baseline: 1.0307x; 1.0307x over previous
//
#include <hip/hip_runtime.h>
#include <stdint.h>

#define DM 1024
#define DF 4096
#define NE 8
#define NTOK 8192   // B*S = 4*2048
#define MT256 40    // >= max 256-row tiles (39), /8

typedef __attribute__((ext_vector_type(8))) short short8;
typedef __attribute__((ext_vector_type(8))) unsigned short ushort8v;
typedef __attribute__((ext_vector_type(4))) float floatx4;

__device__ inline unsigned short f2bf(float f) {
    union { float f; unsigned u; } v; v.f = f;
    unsigned u = v.u;
    u += 0x7fffu + ((u >> 16) & 1u);   // round-to-nearest-even
    return (unsigned short)(u >> 16);
}

#define GLDS(g, l) __builtin_amdgcn_global_load_lds( \
    (const __attribute__((address_space(1))) void*)(g), \
    (__attribute__((address_space(3))) void*)(l), 16, 0, 0)

#define VMW(N)  asm volatile("s_waitcnt vmcnt(" #N ")" ::: "memory")
#define LGKM0   asm volatile("s_waitcnt lgkmcnt(0)" ::: "memory")
#define SCHED0  __builtin_amdgcn_sched_barrier(0)
#define BAR     __builtin_amdgcn_s_barrier()

// ======= fused gate + weight-transpose: one grid, branch on blockIdx =======
// blocks [0, NTOK/4): gating, 4 waves/block, one token per wave, fp64 acc; also emits bf16 x.
// blocks [NTOK/4, ...): LDS-FREE register transpose+convert, one 64x64 tile per block:
//   thread t -> output column n = t&63, k-chunk kc = t>>6. 16 loads, each wave-coalesced
//   (lanes span 64 consecutive n = 256B); convert in-register; store 32B contiguous in k.
//   The n-strided 32B stores combine in per-XCD L2 (k-chunks 0..3 of one n fill a line
//   within this block), keeping HBM writes at the ideal 134 MB. No LDS, no sync.
__global__ __launch_bounds__(256) void gate_transpose(
    const float* __restrict__ x, const float* __restrict__ gw, const float* __restrict__ gb,
    int* __restrict__ top1, unsigned short* __restrict__ xb,
    const float* __restrict__ w1, unsigned short* __restrict__ w1t,
    const float* __restrict__ w2, unsigned short* __restrict__ w2t) {
    constexpr int GATE_BLKS = NTOK / 4;               // 2048
    constexpr int NT1 = NE * (DM / 64) * (DF / 64);   // 8192 tiles per weight
    int bid = blockIdx.x;
    int tid = threadIdx.x;

    if (bid < GATE_BLKS) {
        int wave = tid >> 6, lane = tid & 63;
        int t = bid * 4 + wave;
        const float* xr = x + (size_t)t * DM;
        unsigned short* xbr = xb + (size_t)t * DM;
        double acc[NE];
#pragma unroll
        for (int e = 0; e < NE; ++e) acc[e] = 0.0;
        for (int j = 0; j < DM / 64; ++j) {
            int d = j * 64 + lane;
            float xf = xr[d];
            xbr[d] = f2bf(xf);
            double xv = (double)xf;
            const float* g = gw + (size_t)d * NE;
#pragma unroll
            for (int e = 0; e < NE; ++e) acc[e] = fma(xv, (double)g[e], acc[e]);
        }
#pragma unroll
        for (int e = 0; e < NE; ++e) {
            for (int off = 32; off > 0; off >>= 1)
                acc[e] += __shfl_down(acc[e], off, 64);
        }
        if (lane == 0) {
            int best = 0;
            double bv = acc[0] + (double)gb[0];
            for (int e = 1; e < NE; ++e) {
                double v = acc[e] + (double)gb[e];
                if (v > bv) { bv = v; best = e; }   // strict > == first-max (jnp.argmax)
            }
            top1[t] = best;
        }
        return;
    }

    bid -= GATE_BLKS;
    const float* src; unsigned short* dst; int R, C;
    if (bid < NT1) { src = w1; dst = w1t; R = DM; C = DF; }
    else           { bid -= NT1; src = w2; dst = w2t; R = DF; C = DM; }
    int tilesR = R >> 6, tilesC = C >> 6;
    int e = bid / (tilesR * tilesC);
    int rem = bid % (tilesR * tilesC);
    int tr = rem / tilesC, tc = rem % tilesC;
    const float* s = src + (size_t)e * R * C + (size_t)(tr * 64) * C + tc * 64;
    unsigned short* d = dst + (size_t)e * R * C + (size_t)(tc * 64) * R + tr * 64;
    int nl = tid & 63, kc = tid >> 6;          // kc uniform per wave
    float v[16];
#pragma unroll
    for (int j = 0; j < 16; ++j)
        v[j] = s[(size_t)(kc * 16 + j) * C + nl];
    ushort8v oa, ob;
#pragma unroll
    for (int j = 0; j < 8; ++j) { oa[j] = f2bf(v[j]); ob[j] = f2bf(v[8 + j]); }
    unsigned short* dp = d + (size_t)nl * R + kc * 16;
    *(ushort8v*)(dp) = oa;
    *(ushort8v*)(dp + 8) = ob;
}

// ======= fused count+prefix+scatter+table-build: ONE single-block kernel, LDS state =======
// ctrl ints used downstream: [25] ntiles256, [32+3i..] tile table (expert, rowbase, rows).
__global__ __launch_bounds__(1024) void sort_kernel(const int* __restrict__ top1,
                                                    int* __restrict__ ctrl,
                                                    int* __restrict__ perm) {
    __shared__ int cnt[NE];
    __shared__ int cur[NE];
    int tid = threadIdx.x, lane = tid & 63;
    if (tid < NE) cnt[tid] = 0;
    __syncthreads();
    int ev[8];
#pragma unroll
    for (int j = 0; j < 8; ++j) ev[j] = top1[j * 1024 + tid];
    // wave-ballot counting, one LDS atomic per (wave, expert)
#pragma unroll
    for (int e = 0; e < NE; ++e) {
        int c = 0;
#pragma unroll
        for (int j = 0; j < 8; ++j) {
            unsigned long long m = __ballot(ev[j] == e);
            c += __popcll(m);
        }
        if (lane == 0) atomicAdd(&cnt[e], c);
    }
    __syncthreads();
    if (tid == 0) {
        int s = 0, t256 = 0;
        for (int e = 0; e < NE; ++e) {
            int c = cnt[e];
            cur[e] = s;
            for (int m = 0; m * 256 < c; ++m) {
                ctrl[32 + 3 * t256] = e;
                ctrl[33 + 3 * t256] = s + m * 256;
                int rr = c - m * 256;
                ctrl[34 + 3 * t256] = rr < 256 ? rr : 256;
                ++t256;
            }
            s += c;
        }
        ctrl[25] = t256;
    }
    __syncthreads();
    // scatter: wave-aggregated LDS cursor bumps (order within expert is arbitrary — OK)
#pragma unroll
    for (int j = 0; j < 8; ++j) {
        int e = ev[j];
#pragma unroll
        for (int ex = 0; ex < NE; ++ex) {
            unsigned long long m = __ballot(e == ex);
            if (m == 0ull) continue;
            int leader = __ffsll((long long)m) - 1;
            int base = 0;
            if (lane == leader) base = atomicAdd(&cur[ex], __popcll(m));
            base = __shfl(base, leader, 64);
            if (e == ex) {
                int pos = __popcll(m & ((1ull << lane) - 1ull));
                perm[base + pos] = j * 1024 + tid;   // compacted position -> token id
            }
        }
    }
}

// ================= FFN GEMM: 256x256 tile, 8 waves, ring-4 BK=32 slabs, counted vmcnt ===========
// (round-4 verified-best kernel, restored verbatim after round-6's 128^2 regression)
// LDS slab: [256 rows][4 slots][8 bf16]; slot s' holds global k-chunk s'^((row>>1)&3)
// (pre-swizzled GLOBAL source, linear GLDS dest). Fragment ds_read_b128 -> 2-way banks (free).
// Schedule (T3+T4+T5): stage 3 slabs ahead; ONE s_barrier per slab (32 MFMA/wave/barrier);
// per-wave vmcnt(8) before the slab-end barrier => slab s+1 fully landed after it.
// Ring overwrite safety: slab s+3 -> buf[(s-1)&3], drained before slab s-1's end barrier.
// All ring indices compile-time (x4 unroll + peeled tail); vmcnt ledger counts ONLY the 4
// GLDS/slab. Tail peel: vmcnt 8 / 4 / 0 literals.
#define F_SLAB(u, SU, STG, W) do { \
    if (STG) { \
        int kk_ = ((SU) + 3) * 32; \
        GLDS(ap0 + kk_, &As[((u) + 3) & 3][(size_t)tid * 8]); \
        GLDS(ap1 + kk_, &As[((u) + 3) & 3][(size_t)(512 + tid) * 8]); \
        GLDS(bp0 + kk_, &Bs[((u) + 3) & 3][(size_t)tid * 8]); \
        GLDS(bp1 + kk_, &Bs[((u) + 3) & 3][(size_t)(512 + tid) * 8]); \
    } \
    short8 af[8], bf[4]; \
    _Pragma("unroll") \
    for (int m_ = 0; m_ < 8; ++m_) af[m_] = *(const short8*)&As[u][aoff[m_]]; \
    _Pragma("unroll") \
    for (int n_ = 0; n_ < 4; ++n_) bf[n_] = *(const short8*)&Bs[u][boff[n_]]; \
    LGKM0; SCHED0; \
    __builtin_amdgcn_s_setprio(1); \
    _Pragma("unroll") \
    for (int m_ = 0; m_ < 8; ++m_) \
        _Pragma("unroll") \
        for (int n_ = 0; n_ < 4; ++n_) \
            acc[m_][n_] = __builtin_amdgcn_mfma_f32_16x16x32_bf16(af[m_], bf[n_], acc[m_][n_], 0, 0, 0); \
    __builtin_amdgcn_s_setprio(0); \
    W; SCHED0; BAR; \
} while (0)

template<bool FFN1>
__global__ __launch_bounds__(512, 2) void ffn_gemm(
    const unsigned short* __restrict__ A,    // FFN1: xb [NTOK][DM]; FFN2: H [NTOK][DF] compacted
    const unsigned short* __restrict__ Bt,   // FFN1: w1t [E][DF][DM]; FFN2: w2t [E][DM][DF]
    const float* __restrict__ bias,          // b1 [E][DF] / b2 [E][DM]
    const int* __restrict__ ctrl,
    const int* __restrict__ perm,
    unsigned short* __restrict__ Hout,       // FFN1 out
    float* __restrict__ Yout) {              // FFN2 out
    constexpr int K = FFN1 ? DM : DF;        // 1024 / 4096
    constexpr int N = FFN1 ? DF : DM;        // 4096 / 1024
    constexpr int NT = N / 256;              // 16 / 4
    constexpr int NKI = K / 32;              // 32 / 128 slabs (both divisible by 4)
    constexpr int SLABSZ = 256 * 32;         // ushorts (16 KiB)
    constexpr int G = 8;

    // XCD-bijective remap + nt-major group order
    int nwg = gridDim.x;
    int bo = blockIdx.x;
    int q = nwg >> 3, r = nwg & 7;
    int xcd = bo & 7, lid = bo >> 3;
    int b = (xcd < r ? xcd * (q + 1) : r * (q + 1) + (xcd - r) * q) + lid;

    int grp = b / (G * NT);
    int ii = b % (G * NT);
    int nt = ii / G;
    int til = grp * G + (ii % G);
    if (til >= ctrl[25]) return;
    int e       = ctrl[32 + 3 * til];
    int rowbase = ctrl[33 + 3 * til];
    int rows    = ctrl[34 + 3 * til];

    __shared__ __align__(16) unsigned short As[4][SLABSZ];
    __shared__ __align__(16) unsigned short Bs[4][SLABSZ];

    int tid = threadIdx.x, lane = tid & 63, wave = tid >> 6;
    int wm = (wave >> 2) * 128;   // 0 / 128
    int wn = (wave & 3) * 64;     // 0..192

    // staging: each thread stages 2 rows/slab per operand: rows tid>>2 and 128+(tid>>2)
    int rA0 = tid >> 2, rA1 = 128 + (tid >> 2);
    int kofs = ((tid & 3) ^ ((tid >> 3) & 3)) * 8;   // pre-swizzled global k-chunk
    int c0 = rowbase + (rA0 < rows ? rA0 : rows - 1);
    int c1 = rowbase + (rA1 < rows ? rA1 : rows - 1);
    const unsigned short* ap0;
    const unsigned short* ap1;
    if (FFN1) {
        ap0 = A + (size_t)perm[c0] * K + kofs;
        ap1 = A + (size_t)perm[c1] * K + kofs;
    } else {
        ap0 = A + (size_t)c0 * K + kofs;
        ap1 = A + (size_t)c1 * K + kofs;
    }
    const unsigned short* bb  = Bt + (size_t)e * N * K + (size_t)(nt * 256) * K + kofs;
    const unsigned short* bp0 = bb + (size_t)rA0 * K;
    const unsigned short* bp1 = bb + (size_t)rA1 * K;

    // fragment LDS offsets (ushort units), constant per lane; chunk g=lane>>4 at slot g^((R>>1)&3)
    int aoff[8], boff[4];
#pragma unroll
    for (int m = 0; m < 8; ++m) {
        int R = wm + m * 16 + (lane & 15);
        aoff[m] = R * 32 + (((lane >> 4) ^ ((R >> 1) & 3)) * 8);
    }
#pragma unroll
    for (int n = 0; n < 4; ++n) {
        int R = wn + n * 16 + (lane & 15);
        boff[n] = R * 32 + (((lane >> 4) ^ ((R >> 1) & 3)) * 8);
    }

    floatx4 acc[8][4];
#pragma unroll
    for (int i = 0; i < 8; ++i)
#pragma unroll
        for (int j = 0; j < 4; ++j) acc[i][j] = floatx4{0.f, 0.f, 0.f, 0.f};

    // prologue: stage slabs 0,1,2 (12 GLDS in flight); vmcnt(8) -> slab 0 landed
#pragma unroll
    for (int s = 0; s < 3; ++s) {
        GLDS(ap0 + s * 32, &As[s][(size_t)tid * 8]);
        GLDS(ap1 + s * 32, &As[s][(size_t)(512 + tid) * 8]);
        GLDS(bp0 + s * 32, &Bs[s][(size_t)tid * 8]);
        GLDS(bp1 + s * 32, &Bs[s][(size_t)(512 + tid) * 8]);
    }
    VMW(8); SCHED0; BAR;

#pragma unroll 1
    for (int s = 0; s < NKI - 4; s += 4) {   // each iter: slabs s..s+3, staging s+3..s+6
        F_SLAB(0, s + 0, 1, VMW(8));
        F_SLAB(1, s + 1, 1, VMW(8));
        F_SLAB(2, s + 2, 1, VMW(8));
        F_SLAB(3, s + 3, 1, VMW(8));
    }
    // tail: slabs NKI-4..NKI-1 (first stages slab NKI-1; then drain 8 -> 4 -> 0)
    F_SLAB(0, NKI - 4, 1, VMW(8));
    F_SLAB(1, NKI - 3, 0, VMW(4));
    F_SLAB(2, NKI - 2, 0, VMW(0));
    F_SLAB(3, NKI - 1, 0, (void)0);

    // epilogue; C/D layout: col = lane&15, row = (lane>>4)*4 + reg
    int col0 = nt * 256 + wn + (lane & 15);
    int rowq = (lane >> 4) * 4;
    float bv[4];
#pragma unroll
    for (int n = 0; n < 4; ++n) bv[n] = bias[e * N + col0 + n * 16];

#pragma unroll
    for (int m = 0; m < 8; ++m) {
#pragma unroll
        for (int r2 = 0; r2 < 4; ++r2) {
            int lr = wm + m * 16 + rowq + r2;
            if (lr < rows) {
                if (FFN1) {
                    unsigned short* hr = Hout + (size_t)(rowbase + lr) * DF + col0;
#pragma unroll
                    for (int n = 0; n < 4; ++n) {
                        float v = acc[m][n][r2] + bv[n];
                        v = v > 0.f ? v : 0.f;
                        hr[n * 16] = f2bf(v);
                    }
                } else {
                    float* yr = Yout + (size_t)perm[rowbase + lr] * DM + col0;
#pragma unroll
                    for (int n = 0; n < 4; ++n)
                        yr[n * 16] = acc[m][n][r2] + bv[n];
                }
            }
        }
    }
}
#undef F_SLAB

extern "C" void kernel_launch(void* const* d_in, const int* in_sizes, int n_in,
                              void* d_out, int out_size, void* d_ws, size_t ws_size,
                              hipStream_t stream) {
    const float* x  = (const float*)d_in[0];
    const float* w1 = (const float*)d_in[1];
    const float* b1 = (const float*)d_in[2];
    const float* w2 = (const float*)d_in[3];
    const float* b2 = (const float*)d_in[4];
    const float* gw = (const float*)d_in[5];
    const float* gb = (const float*)d_in[6];
    float* out = (float*)d_out;

    // workspace carve-up
    char* ws = (char*)d_ws;
    int* ctrl = (int*)ws;                                   // 2 KiB control block
    int* top1 = (int*)(ws + 2048);                          // 8192 ints
    int* perm = (int*)(ws + 2048 + 32768);                  // 8192 ints
    size_t o = 67584;                                       // 256B-aligned
    unsigned short* xb  = (unsigned short*)(ws + o);        o += (size_t)NTOK * DM * 2;      // 16.8 MB
    unsigned short* w1t = (unsigned short*)(ws + o);        o += (size_t)NE * DM * DF * 2;   // 67 MB
    unsigned short* w2t = (unsigned short*)(ws + o);        o += (size_t)NE * DM * DF * 2;   // 67 MB
    unsigned short* H   = (unsigned short*)(ws + o);        // 67 MB  (total ~218 MB)

    // 4 dispatches: fused gate+transpose, fused sort, ffn1, ffn2
    gate_transpose<<<NTOK / 4 + 2 * NE * (DM / 64) * (DF / 64), 256, 0, stream>>>(
        x, gw, gb, top1, xb, w1, w1t, w2, w2t);
    sort_kernel<<<1, 1024, 0, stream>>>(top1, ctrl, perm);
    ffn_gemm<true ><<<MT256 * (DF / 256), 512, 0, stream>>>(xb, w1t, b1, ctrl, perm, H, nullptr);
    ffn_gemm<false><<<MT256 * (DM / 256), 512, 0, stream>>>(H, w2t, b2, ctrl, perm, nullptr, out);
}